// Round 1
// baseline (1490.432 us; speedup 1.0000x reference)
//
#include <hip/hip_runtime.h>

// Problem constants (fixed by setup_inputs)
#define N0V 1000000
#define N1V 400000
#define N2V 100000
#define E0V 2000000
#define E1V 500000
#define DD  128
#define HH  50
#define FP  64    // padded feature dim
#define KC  32    // k-chunk staged in LDS
#define NB_SCAN 1563   // ceil(N1V/256)

// Workspace layout (byte offsets, all 16B-aligned)
#define OFF_DEG    0ULL                 // N1 int  = 1,600,000
#define OFF_SSUM   1600000ULL           // N2 f32  =   400,000
#define OFF_CNT2   2000000ULL           // N2 f32  =   400,000
#define ZERO_BYTES 2400000ULL
#define OFF_ROWPTR 2400000ULL           // N1 int  = 1,600,000
#define OFF_CURSOR 4000000ULL           // N1 int  = 1,600,000
#define OFF_BSUM   5600000ULL           // NB_SCAN int (pad to 8192 B)
#define OFF_SMALL  5608192ULL           // bl1p[64], wAp[64], wBp[64], c : 1024 B
#define OFF_WL1P   5609216ULL           // 128*64 f32 = 32,768
#define OFF_WR1P   5641984ULL           // 128*64 f32 = 32,768
#define OFF_S      5674752ULL           // N1 f32 = 1,600,000
#define OFF_T      7274752ULL           // N2 f32 =   400,000
#define OFF_CSR    7674752ULL           // E0 int = 8,000,000
#define OFF_AGG    15674752ULL          // N1*FP f32 = 102,400,000 (stores MEAN)
#define OFF_Y      118074752ULL         // N0*FP bf16 = 128,000,000
#define WS_NEEDED  246074752ULL

__device__ inline unsigned short f2bf(float f) {
    unsigned int u = __float_as_uint(f);
    unsigned int r = (u + 0x7FFFu + ((u >> 16) & 1u)) >> 16;
    return (unsigned short)r;
}

// K0: pad Wl1/Wr1 to [128][64] (zeros), build bl1p/wAp/wBp (padded) and c.
__global__ void pad_w(const float* __restrict__ Wl1, const float* __restrict__ Wr1,
                      const float* __restrict__ bl1,
                      const float* __restrict__ Wl2, const float* __restrict__ bl2,
                      const float* __restrict__ Wr2, const float* __restrict__ Wo,
                      const float* __restrict__ bo,
                      float* __restrict__ Wl1p, float* __restrict__ Wr1p,
                      float* __restrict__ smalls)
{
    int gid = blockIdx.x * 256 + threadIdx.x;   // 32 blocks -> 8192 threads
    if (gid < 128 * FP) {
        int k = gid >> 6, f = gid & 63;
        float a = (f < HH) ? Wl1[k * HH + f] : 0.f;
        float b = (f < HH) ? Wr1[k * HH + f] : 0.f;
        Wl1p[gid] = a;
        Wr1p[gid] = b;
    }
    if (gid < FP) {
        float a = 0.f, b = 0.f;
        if (gid < HH) {
            for (int g = 0; g < HH; ++g) {
                float w = Wo[g];
                a += Wl2[gid * HH + g] * w;
                b += Wr2[gid * HH + g] * w;
            }
        }
        smalls[gid]          = (gid < HH) ? bl1[gid] : 0.f;  // bl1p
        smalls[FP + gid]     = a;                             // wAp
        smalls[2 * FP + gid] = b;                             // wBp
    }
    if (gid == 0) {
        float c = bo[0];
        for (int g = 0; g < HH; ++g) c += bl2[g] * Wo[g];
        smalls[3 * FP] = c;
    }
}

// K1: y = x @ Wl1p, output packed bf16, rows padded to 64 feats (128 B).
__global__ __launch_bounds__(256, 4) void gemm_y(const float* __restrict__ X,
                                                 const float* __restrict__ Wp,
                                                 unsigned int* __restrict__ Ybf)
{
    __shared__ float xs[KC * 256];   // 32 KB
    const int t  = threadIdx.x;
    const int n0 = blockIdx.x * 256;
    const int ng = t >> 3;           // 0..31
    const int fg = t & 7;            // 0..7
    const int nbase = n0 + ng * 8;

    float acc[8][8];
#pragma unroll
    for (int i = 0; i < 8; ++i)
#pragma unroll
        for (int j = 0; j < 8; ++j) acc[i][j] = 0.f;

    for (int c = 0; c < DD / KC; ++c) {
        if (c) __syncthreads();
#pragma unroll
        for (int j = 0; j < 8; ++j) {
            int f4  = j * 256 + t;
            int row = f4 >> 3;
            int c4  = f4 & 7;
            int gn  = n0 + row;
            float4 v = make_float4(0.f, 0.f, 0.f, 0.f);
            if (gn < N0V) v = *(const float4*)(X + (size_t)gn * DD + c * KC + c4 * 4);
            int kb  = c4 * 4;
            int rsw = row ^ (c4 << 3);           // swizzle by (k>>2)
            xs[(kb + 0) * 256 + rsw] = v.x;
            xs[(kb + 1) * 256 + rsw] = v.y;
            xs[(kb + 2) * 256 + rsw] = v.z;
            xs[(kb + 3) * 256 + rsw] = v.w;
        }
        __syncthreads();
#pragma unroll 4
        for (int kk = 0; kk < KC; ++kk) {
            int m = kk >> 2;
            const float* xp = &xs[kk * 256 + ((ng ^ m) << 3)];
            float4 x0 = *(const float4*)xp;
            float4 x1 = *(const float4*)(xp + 4);
            const float* wr = Wp + (size_t)(c * KC + kk) * FP + fg * 8;
            float4 w0 = *(const float4*)wr;
            float4 w1 = *(const float4*)(wr + 4);
            float xv[8] = {x0.x, x0.y, x0.z, x0.w, x1.x, x1.y, x1.z, x1.w};
            float wv[8] = {w0.x, w0.y, w0.z, w0.w, w1.x, w1.y, w1.z, w1.w};
#pragma unroll
            for (int i = 0; i < 8; ++i)
#pragma unroll
                for (int j = 0; j < 8; ++j)
                    acc[i][j] = fmaf(xv[i], wv[j], acc[i][j]);
        }
    }

    if (nbase < N0V) {   // N0 % 8 == 0 -> group fully valid
#pragma unroll
        for (int i = 0; i < 8; ++i) {
            uint4 q;
            q.x = (unsigned)f2bf(acc[i][0]) | ((unsigned)f2bf(acc[i][1]) << 16);
            q.y = (unsigned)f2bf(acc[i][2]) | ((unsigned)f2bf(acc[i][3]) << 16);
            q.z = (unsigned)f2bf(acc[i][4]) | ((unsigned)f2bf(acc[i][5]) << 16);
            q.w = (unsigned)f2bf(acc[i][6]) | ((unsigned)f2bf(acc[i][7]) << 16);
            *(uint4*)(Ybf + (size_t)(nbase + i) * 32 + fg * 4) = q;
        }
    }
}

// K2a: degree histogram of dst0
__global__ __launch_bounds__(256) void hist1(const int* __restrict__ dst,
                                             int* __restrict__ deg)
{
    int e = blockIdx.x * 256 + threadIdx.x;
    if (e < E0V) atomicAdd(&deg[dst[e]], 1);
}

// K2b: per-block inclusive scan of deg -> incl (in rowptr), block totals -> bsum
__global__ __launch_bounds__(256) void scan_a(const int* __restrict__ deg,
                                              int* __restrict__ incl,
                                              int* __restrict__ bsum)
{
    __shared__ int s[256];
    int tid = threadIdx.x;
    int i = blockIdx.x * 256 + tid;
    int v = (i < N1V) ? deg[i] : 0;
    s[tid] = v;
    __syncthreads();
#pragma unroll
    for (int off = 1; off < 256; off <<= 1) {
        int tv = (tid >= off) ? s[tid - off] : 0;
        __syncthreads();
        s[tid] += tv;
        __syncthreads();
    }
    if (i < N1V) incl[i] = s[tid];
    if (tid == 255) bsum[blockIdx.x] = s[255];
}

// K2c: exclusive scan of block sums (single block, sequential chunks)
__global__ __launch_bounds__(256) void scan_b(int* __restrict__ bsum)
{
    __shared__ int s[256];
    __shared__ int run_s;
    int tid = threadIdx.x;
    if (tid == 0) run_s = 0;
    __syncthreads();
    for (int base = 0; base < NB_SCAN; base += 256) {
        int idx = base + tid;
        int v = (idx < NB_SCAN) ? bsum[idx] : 0;
        s[tid] = v;
        __syncthreads();
#pragma unroll
        for (int off = 1; off < 256; off <<= 1) {
            int tv = (tid >= off) ? s[tid - off] : 0;
            __syncthreads();
            s[tid] += tv;
            __syncthreads();
        }
        int rbase = run_s;
        if (idx < NB_SCAN) bsum[idx] = s[tid] - v + rbase;
        __syncthreads();
        if (tid == 255) run_s = rbase + s[255];
        __syncthreads();
    }
}

// K2d: rowptr[i] = incl[i] - deg[i] + bsum[block]  (exclusive); cursor = copy
__global__ __launch_bounds__(256) void scan_c(const int* __restrict__ deg,
                                              int* __restrict__ rowptr,
                                              int* __restrict__ cursor,
                                              const int* __restrict__ bsum)
{
    int i = blockIdx.x * 256 + threadIdx.x;
    if (i < N1V) {
        int ex = rowptr[i] - deg[i] + bsum[blockIdx.x];
        rowptr[i] = ex;
        cursor[i] = ex;
    }
}

// K2e: fill CSR: csr[atomic cursor[dst]] = src
__global__ __launch_bounds__(256) void fill1(const int* __restrict__ src,
                                             const int* __restrict__ dst,
                                             int* __restrict__ cursor,
                                             int* __restrict__ csr)
{
    int e = blockIdx.x * 256 + threadIdx.x;
    if (e < E0V) {
        int d = dst[e];
        int pos = atomicAdd(&cursor[d], 1);
        csr[pos] = src[e];
    }
}

// K3: gather-mean: agg[n][0:64] = mean over neighbors of y[src] (bf16 -> f32)
// half-wave (32 lanes) per node; lane handles 2 features (one packed uint)
// Unrolled by 2: two independent 128B row loads in flight per iteration (MLP).
__global__ __launch_bounds__(256) void gather1(const unsigned int* __restrict__ Ybf,
                                               const int* __restrict__ rowptr,
                                               const int* __restrict__ deg,
                                               const int* __restrict__ csr,
                                               float* __restrict__ agg)
{
    int node = blockIdx.x * 8 + (threadIdx.x >> 5);
    int lane = threadIdx.x & 31;
    if (node >= N1V) return;
    int start = rowptr[node];
    int dg = deg[node];
    float a0 = 0.f, a1 = 0.f, b0 = 0.f, b1 = 0.f;
    int k = 0;
    for (; k + 1 < dg; k += 2) {
        int s0 = csr[start + k];
        int s1 = csr[start + k + 1];
        unsigned v0 = Ybf[(size_t)s0 * 32 + lane];
        unsigned v1 = Ybf[(size_t)s1 * 32 + lane];
        a0 += __uint_as_float(v0 << 16);
        a1 += __uint_as_float(v0 & 0xFFFF0000u);
        b0 += __uint_as_float(v1 << 16);
        b1 += __uint_as_float(v1 & 0xFFFF0000u);
    }
    if (k < dg) {
        int s0 = csr[start + k];
        unsigned v0 = Ybf[(size_t)s0 * 32 + lane];
        a0 += __uint_as_float(v0 << 16);
        a1 += __uint_as_float(v0 & 0xFFFF0000u);
    }
    a0 += b0;
    a1 += b1;
    float inv = 1.0f / (float)max(dg, 1);
    *(float2*)(agg + (size_t)node * FP + lane * 2) = make_float2(a0 * inv, a1 * inv);
}

// K4: d = x[:N1] @ Wr1p (tiled GEMM), epilogue:
//   h = relu(aggmean + bl1 + d);  s = h.wA;  t = h.wB  (shfl-reduce over 8 fgs)
__global__ __launch_bounds__(256, 4) void node_l1(const float* __restrict__ X,
                                                  const float* __restrict__ Wp,
                                                  const float* __restrict__ agg,
                                                  const float* __restrict__ smalls,
                                                  float* __restrict__ sArr,
                                                  float* __restrict__ tArr)
{
    __shared__ float xs[KC * 256];
    const int t  = threadIdx.x;
    const int n0 = blockIdx.x * 256;
    const int ng = t >> 3;
    const int fg = t & 7;
    const int nbase = n0 + ng * 8;

    float acc[8][8];
#pragma unroll
    for (int i = 0; i < 8; ++i)
#pragma unroll
        for (int j = 0; j < 8; ++j) acc[i][j] = 0.f;

    for (int c = 0; c < DD / KC; ++c) {
        if (c) __syncthreads();
#pragma unroll
        for (int j = 0; j < 8; ++j) {
            int f4  = j * 256 + t;
            int row = f4 >> 3;
            int c4  = f4 & 7;
            int gn  = n0 + row;
            float4 v = make_float4(0.f, 0.f, 0.f, 0.f);
            if (gn < N1V) v = *(const float4*)(X + (size_t)gn * DD + c * KC + c4 * 4);
            int kb  = c4 * 4;
            int rsw = row ^ (c4 << 3);
            xs[(kb + 0) * 256 + rsw] = v.x;
            xs[(kb + 1) * 256 + rsw] = v.y;
            xs[(kb + 2) * 256 + rsw] = v.z;
            xs[(kb + 3) * 256 + rsw] = v.w;
        }
        __syncthreads();
#pragma unroll 4
        for (int kk = 0; kk < KC; ++kk) {
            int m = kk >> 2;
            const float* xp = &xs[kk * 256 + ((ng ^ m) << 3)];
            float4 x0 = *(const float4*)xp;
            float4 x1 = *(const float4*)(xp + 4);
            const float* wr = Wp + (size_t)(c * KC + kk) * FP + fg * 8;
            float4 w0 = *(const float4*)wr;
            float4 w1 = *(const float4*)(wr + 4);
            float xv[8] = {x0.x, x0.y, x0.z, x0.w, x1.x, x1.y, x1.z, x1.w};
            float wv[8] = {w0.x, w0.y, w0.z, w0.w, w1.x, w1.y, w1.z, w1.w};
#pragma unroll
            for (int i = 0; i < 8; ++i)
#pragma unroll
                for (int j = 0; j < 8; ++j)
                    acc[i][j] = fmaf(xv[i], wv[j], acc[i][j]);
        }
    }

    if (nbase >= N1V) return;   // no further barriers

    const float* blp = smalls + fg * 8;
    const float* wAp = smalls + FP + fg * 8;
    const float* wBp = smalls + 2 * FP + fg * 8;
    float bl_r[8], wA_r[8], wB_r[8];
#pragma unroll
    for (int j = 0; j < 8; ++j) { bl_r[j] = blp[j]; wA_r[j] = wAp[j]; wB_r[j] = wBp[j]; }

    float ps[8], pt[8];
#pragma unroll
    for (int i = 0; i < 8; ++i) {
        int n = nbase + i;
        const float* ar = agg + (size_t)n * FP + fg * 8;
        float4 a0 = *(const float4*)ar;
        float4 a1 = *(const float4*)(ar + 4);
        float agf[8] = {a0.x, a0.y, a0.z, a0.w, a1.x, a1.y, a1.z, a1.w};
        float s_acc = 0.f, t_acc = 0.f;
#pragma unroll
        for (int j = 0; j < 8; ++j) {
            float h = fmaxf(agf[j] + bl_r[j] + acc[i][j], 0.f);
            s_acc = fmaf(h, wA_r[j], s_acc);
            t_acc = fmaf(h, wB_r[j], t_acc);
        }
        ps[i] = s_acc; pt[i] = t_acc;
    }
#pragma unroll
    for (int i = 0; i < 8; ++i) {
#pragma unroll
        for (int m = 1; m < 8; m <<= 1) {
            ps[i] += __shfl_xor(ps[i], m);
            pt[i] += __shfl_xor(pt[i], m);
        }
    }
    if (fg == 0) {
#pragma unroll
        for (int i = 0; i < 8; ++i) sArr[nbase + i] = ps[i];
        if (nbase < N2V) {
#pragma unroll
            for (int i = 0; i < 8; ++i) tArr[nbase + i] = pt[i];
        }
    }
}

// K5: edge scatter layer 2 (scalar atomics; only 500k edges)
__global__ __launch_bounds__(256) void scatter2(const float* __restrict__ sArr,
                                                const int* __restrict__ src,
                                                const int* __restrict__ dst,
                                                float* __restrict__ ssum,
                                                float* __restrict__ cnt2)
{
    int e = blockIdx.x * 256 + threadIdx.x;
    if (e >= E1V) return;
    int sI = src[e];
    int dI = dst[e];
    atomicAdd(&ssum[dI], sArr[sI]);
    atomicAdd(&cnt2[dI], 1.0f);
}

// K6: out[i] = relu(ssum[i]/max(cnt2,1) + t[i] + c)
__global__ __launch_bounds__(256) void final_out(const float* __restrict__ ssum,
                                                 const float* __restrict__ cnt2,
                                                 const float* __restrict__ tArr,
                                                 const float* __restrict__ smalls,
                                                 float* __restrict__ out)
{
    int i = blockIdx.x * 256 + threadIdx.x;
    if (i >= N2V) return;
    float c = smalls[3 * FP];
    float inv = 1.0f / fmaxf(cnt2[i], 1.0f);
    float o = fmaf(ssum[i], inv, tArr[i] + c);
    out[i] = fmaxf(o, 0.f);
}

extern "C" void kernel_launch(void* const* d_in, const int* in_sizes, int n_in,
                              void* d_out, int out_size, void* d_ws, size_t ws_size,
                              hipStream_t stream)
{
    if (ws_size < WS_NEEDED) return;

    const float* x    = (const float*)d_in[0];
    const int*   src0 = (const int*)d_in[2];
    const int*   dst0 = (const int*)d_in[3];
    const int*   src1 = (const int*)d_in[4];
    const int*   dst1 = (const int*)d_in[5];
    const float* Wl1  = (const float*)d_in[8];
    const float* bl1  = (const float*)d_in[9];
    const float* Wr1  = (const float*)d_in[10];
    const float* Wl2  = (const float*)d_in[11];
    const float* bl2  = (const float*)d_in[12];
    const float* Wr2  = (const float*)d_in[13];
    const float* Wo   = (const float*)d_in[14];
    const float* bo   = (const float*)d_in[15];
    float* out = (float*)d_out;

    char* ws = (char*)d_ws;
    int*   deg    = (int*)(ws + OFF_DEG);
    float* ssum   = (float*)(ws + OFF_SSUM);
    float* cnt2   = (float*)(ws + OFF_CNT2);
    int*   rowptr = (int*)(ws + OFF_ROWPTR);
    int*   cursor = (int*)(ws + OFF_CURSOR);
    int*   bsum   = (int*)(ws + OFF_BSUM);
    float* smalls = (float*)(ws + OFF_SMALL);
    float* Wl1p   = (float*)(ws + OFF_WL1P);
    float* Wr1p   = (float*)(ws + OFF_WR1P);
    float* sArr   = (float*)(ws + OFF_S);
    float* tArr   = (float*)(ws + OFF_T);
    int*   csr    = (int*)(ws + OFF_CSR);
    float* agg    = (float*)(ws + OFF_AGG);
    unsigned int* ybf = (unsigned int*)(ws + OFF_Y);

    hipMemsetAsync(d_ws, 0, ZERO_BYTES, stream);

    pad_w<<<32, 256, 0, stream>>>(Wl1, Wr1, bl1, Wl2, bl2, Wr2, Wo, bo, Wl1p, Wr1p, smalls);

    gemm_y<<<(N0V + 255) / 256, 256, 0, stream>>>(x, Wl1p, ybf);

    // CSR build for layer-1 edges
    hist1<<<(E0V + 255) / 256, 256, 0, stream>>>(dst0, deg);
    scan_a<<<NB_SCAN, 256, 0, stream>>>(deg, rowptr, bsum);
    scan_b<<<1, 256, 0, stream>>>(bsum);
    scan_c<<<NB_SCAN, 256, 0, stream>>>(deg, rowptr, cursor, bsum);
    fill1<<<(E0V + 255) / 256, 256, 0, stream>>>(src0, dst0, cursor, csr);

    gather1<<<(N1V + 7) / 8, 256, 0, stream>>>(ybf, rowptr, deg, csr, agg);

    node_l1<<<NB_SCAN, 256, 0, stream>>>(x, Wr1p, agg, smalls, sArr, tArr);

    scatter2<<<(E1V + 255) / 256, 256, 0, stream>>>(sArr, src1, dst1, ssum, cnt2);

    final_out<<<(N2V + 255) / 256, 256, 0, stream>>>(ssum, cnt2, tArr, smalls, out);
}

// Round 2
// 1236.758 us; speedup vs baseline: 1.2051x; 1.2051x over previous
//
#include <hip/hip_runtime.h>

// Problem constants (fixed by setup_inputs)
#define N0V 1000000
#define N1V 400000
#define N2V 100000
#define E0V 2000000
#define E1V 500000
#define DD  128
#define HH  50
#define FP  64    // padded feature dim
#define NB_SCAN 1563   // ceil(N1V/256)

// Workspace layout (byte offsets, all 16B-aligned)
#define OFF_DEG    0ULL                 // N1 int  = 1,600,000
#define OFF_SSUM   1600000ULL           // N2 f32  =   400,000
#define OFF_CNT2   2000000ULL           // N2 f32  =   400,000
#define ZERO_BYTES 2400000ULL
#define OFF_ROWPTR 2400000ULL           // N1 int  = 1,600,000
#define OFF_CURSOR 4000000ULL           // N1 int  = 1,600,000
#define OFF_BSUM   5600000ULL           // NB_SCAN int (pad to 8192 B)
#define OFF_SMALL  5608192ULL           // bl1p[64], wAp[64], wBp[64], c : 1024 B
#define OFF_WLT    5609216ULL           // 64*128 f16 = 16,384 B (transposed [n][k])
#define OFF_WRT    5625600ULL           // 64*128 f16 = 16,384 B
#define OFF_S      5641984ULL           // N1 f32 = 1,600,000
#define OFF_T      7241984ULL           // N2 f32 =   400,000
#define OFF_CSR    7641984ULL           // E0 int = 8,000,000
#define OFF_AGG    15641984ULL          // N1*FP f16 = 51,200,000
#define OFF_D      66841984ULL          // N1*FP f16 = 51,200,000
#define OFF_Y      118041984ULL         // N0*FP f16 = 128,000,000
#define WS_NEEDED  246041984ULL

typedef _Float16 half8 __attribute__((ext_vector_type(8)));
typedef _Float16 half4 __attribute__((ext_vector_type(4)));
typedef float    f32x4 __attribute__((ext_vector_type(4)));

__device__ inline unsigned pack2h(float a, float b) {
    union { _Float16 h[2]; unsigned u; } cv;
    cv.h[0] = (_Float16)a;
    cv.h[1] = (_Float16)b;
    return cv.u;
}
__device__ inline float2 unp2h(unsigned v) {
    union { unsigned u; _Float16 h[2]; } cv;
    cv.u = v;
    return make_float2((float)cv.h[0], (float)cv.h[1]);
}

// K0: build transposed f16 weights Wlt/Wrt [64 n][128 k]; smalls (f32) as before.
__global__ void pad_w(const float* __restrict__ Wl1, const float* __restrict__ Wr1,
                      const float* __restrict__ bl1,
                      const float* __restrict__ Wl2, const float* __restrict__ bl2,
                      const float* __restrict__ Wr2, const float* __restrict__ Wo,
                      const float* __restrict__ bo,
                      _Float16* __restrict__ Wlt, _Float16* __restrict__ Wrt,
                      float* __restrict__ smalls)
{
    int gid = blockIdx.x * 256 + threadIdx.x;   // 32 blocks -> 8192 threads
    if (gid < 64 * 128) {
        int n = gid >> 7, k = gid & 127;
        float a = (n < HH) ? Wl1[k * HH + n] : 0.f;
        float b = (n < HH) ? Wr1[k * HH + n] : 0.f;
        Wlt[gid] = (_Float16)a;
        Wrt[gid] = (_Float16)b;
    }
    if (gid < FP) {
        float a = 0.f, b = 0.f;
        if (gid < HH) {
            for (int g = 0; g < HH; ++g) {
                float w = Wo[g];
                a += Wl2[gid * HH + g] * w;
                b += Wr2[gid * HH + g] * w;
            }
        }
        smalls[gid]          = (gid < HH) ? bl1[gid] : 0.f;  // bl1p
        smalls[FP + gid]     = a;                             // wAp
        smalls[2 * FP + gid] = b;                             // wBp
    }
    if (gid == 0) {
        float c = bo[0];
        for (int g = 0; g < HH; ++g) c += bl2[g] * Wo[g];
        smalls[3 * FP] = c;
    }
}

// K1: fused MFMA GEMM.
//   Yh[n][64] f16 = x @ Wl1            (all N0 rows)
//   Dh[n][64] f16 = x @ Wr1            (rows < N1 only; N1 % 128 == 0)
// Swapped-operand mfma: D'[feat][node] = mfma(Wt-frag, X-frag) so each lane
// holds 4 consecutive feats of one node -> direct packed f16 stores.
__global__ __launch_bounds__(256, 3) void fused_gemm(
    const float* __restrict__ X,
    const _Float16* __restrict__ Wlt,
    const _Float16* __restrict__ Wrt,
    unsigned int* __restrict__ Yh,
    unsigned int* __restrict__ Dh)
{
    __shared__ _Float16 xs[128][72];   // 18,432 B, +8 halfs pad (bank-safe)
    const int t  = threadIdx.x;
    const int w  = t >> 6;          // wave 0..3
    const int l  = t & 63;
    const int lr = l & 15;          // row-in-tile (feat for W, node for X)
    const int lk = l >> 4;          // k-subgroup 0..3
    const int n0 = blockIdx.x * 128;
    const bool hasD = (blockIdx.x < N1V / 128);   // 3125 full-D blocks

    f32x4 yacc[4][2], dacc[4][2];
#pragma unroll
    for (int ft = 0; ft < 4; ++ft)
#pragma unroll
        for (int mt = 0; mt < 2; ++mt) {
            yacc[ft][mt] = (f32x4){0.f, 0.f, 0.f, 0.f};
            dacc[ft][mt] = (f32x4){0.f, 0.f, 0.f, 0.f};
        }

    const int srow = t >> 4;        // 0..15
    const int scol = t & 15;        // float4 index along 64-col chunk

    for (int c = 0; c < 2; ++c) {   // two K-chunks of 64
        if (c) __syncthreads();
#pragma unroll
        for (int p = 0; p < 8; ++p) {
            int row = p * 16 + srow;
            int gn  = n0 + row;
            float4 v = make_float4(0.f, 0.f, 0.f, 0.f);
            if (gn < N0V) v = *(const float4*)(X + (size_t)gn * DD + c * 64 + scol * 4);
            half4 h = { (_Float16)v.x, (_Float16)v.y, (_Float16)v.z, (_Float16)v.w };
            *(half4*)(&xs[row][scol * 4]) = h;
        }
        __syncthreads();
#pragma unroll
        for (int ks = 0; ks < 2; ++ks) {
            half8 xf[2];
#pragma unroll
            for (int mt = 0; mt < 2; ++mt)
                xf[mt] = *(const half8*)(&xs[w * 32 + mt * 16 + lr][ks * 32 + lk * 8]);
            const int kg = c * 64 + ks * 32 + lk * 8;
#pragma unroll
            for (int ft = 0; ft < 4; ++ft) {
                half8 wl = *(const half8*)(Wlt + (ft * 16 + lr) * 128 + kg);
#pragma unroll
                for (int mt = 0; mt < 2; ++mt)
                    yacc[ft][mt] = __builtin_amdgcn_mfma_f32_16x16x32_f16(
                        wl, xf[mt], yacc[ft][mt], 0, 0, 0);
            }
            if (hasD) {
#pragma unroll
                for (int ft = 0; ft < 4; ++ft) {
                    half8 wr = *(const half8*)(Wrt + (ft * 16 + lr) * 128 + kg);
#pragma unroll
                    for (int mt = 0; mt < 2; ++mt)
                        dacc[ft][mt] = __builtin_amdgcn_mfma_f32_16x16x32_f16(
                            wr, xf[mt], dacc[ft][mt], 0, 0, 0);
                }
            }
        }
    }

    // stores: lane -> node = n0 + w*32 + mt*16 + lr ; feats ft*16 + lk*4 + j
#pragma unroll
    for (int mt = 0; mt < 2; ++mt) {
        int node = n0 + w * 32 + mt * 16 + lr;
        if (node >= N0V) continue;
        unsigned int* yp = Yh + (size_t)node * 32 + lk * 2;
#pragma unroll
        for (int ft = 0; ft < 4; ++ft) {
            f32x4 a = yacc[ft][mt];
            uint2 q;
            q.x = pack2h(a[0], a[1]);
            q.y = pack2h(a[2], a[3]);
            *(uint2*)(yp + ft * 8) = q;
        }
        if (hasD) {
            unsigned int* dp = Dh + (size_t)node * 32 + lk * 2;
#pragma unroll
            for (int ft = 0; ft < 4; ++ft) {
                f32x4 a = dacc[ft][mt];
                uint2 q;
                q.x = pack2h(a[0], a[1]);
                q.y = pack2h(a[2], a[3]);
                *(uint2*)(dp + ft * 8) = q;
            }
        }
    }
}

// K2a: degree histogram of dst0
__global__ __launch_bounds__(256) void hist1(const int* __restrict__ dst,
                                             int* __restrict__ deg)
{
    int e = blockIdx.x * 256 + threadIdx.x;
    if (e < E0V) atomicAdd(&deg[dst[e]], 1);
}

// K2b: per-block inclusive scan of deg -> incl (in rowptr), block totals -> bsum
__global__ __launch_bounds__(256) void scan_a(const int* __restrict__ deg,
                                              int* __restrict__ incl,
                                              int* __restrict__ bsum)
{
    __shared__ int s[256];
    int tid = threadIdx.x;
    int i = blockIdx.x * 256 + tid;
    int v = (i < N1V) ? deg[i] : 0;
    s[tid] = v;
    __syncthreads();
#pragma unroll
    for (int off = 1; off < 256; off <<= 1) {
        int tv = (tid >= off) ? s[tid - off] : 0;
        __syncthreads();
        s[tid] += tv;
        __syncthreads();
    }
    if (i < N1V) incl[i] = s[tid];
    if (tid == 255) bsum[blockIdx.x] = s[255];
}

// K2c: exclusive scan of block sums (single block, sequential chunks)
__global__ __launch_bounds__(256) void scan_b(int* __restrict__ bsum)
{
    __shared__ int s[256];
    __shared__ int run_s;
    int tid = threadIdx.x;
    if (tid == 0) run_s = 0;
    __syncthreads();
    for (int base = 0; base < NB_SCAN; base += 256) {
        int idx = base + tid;
        int v = (idx < NB_SCAN) ? bsum[idx] : 0;
        s[tid] = v;
        __syncthreads();
#pragma unroll
        for (int off = 1; off < 256; off <<= 1) {
            int tv = (tid >= off) ? s[tid - off] : 0;
            __syncthreads();
            s[tid] += tv;
            __syncthreads();
        }
        int rbase = run_s;
        if (idx < NB_SCAN) bsum[idx] = s[tid] - v + rbase;
        __syncthreads();
        if (tid == 255) run_s = rbase + s[255];
        __syncthreads();
    }
}

// K2d: rowptr[i] = incl[i] - deg[i] + bsum[block]  (exclusive); cursor = copy
__global__ __launch_bounds__(256) void scan_c(const int* __restrict__ deg,
                                              int* __restrict__ rowptr,
                                              int* __restrict__ cursor,
                                              const int* __restrict__ bsum)
{
    int i = blockIdx.x * 256 + threadIdx.x;
    if (i < N1V) {
        int ex = rowptr[i] - deg[i] + bsum[blockIdx.x];
        rowptr[i] = ex;
        cursor[i] = ex;
    }
}

// K2e: fill CSR: csr[atomic cursor[dst]] = src
__global__ __launch_bounds__(256) void fill1(const int* __restrict__ src,
                                             const int* __restrict__ dst,
                                             int* __restrict__ cursor,
                                             int* __restrict__ csr)
{
    int e = blockIdx.x * 256 + threadIdx.x;
    if (e < E0V) {
        int d = dst[e];
        int pos = atomicAdd(&cursor[d], 1);
        csr[pos] = src[e];
    }
}

// K3: gather-mean: agg[n][0:64] (f16 packed) = mean over neighbors of y[src]
// half-wave (32 lanes) per node; lane handles 2 features (one packed uint);
// 2-way unroll keeps two independent 128B row loads in flight.
__global__ __launch_bounds__(256) void gather1(const unsigned int* __restrict__ Yh,
                                               const int* __restrict__ rowptr,
                                               const int* __restrict__ deg,
                                               const int* __restrict__ csr,
                                               unsigned int* __restrict__ aggh)
{
    int node = blockIdx.x * 8 + (threadIdx.x >> 5);
    int lane = threadIdx.x & 31;
    if (node >= N1V) return;
    int start = rowptr[node];
    int dg = deg[node];
    float a0 = 0.f, a1 = 0.f, b0 = 0.f, b1 = 0.f;
    int k = 0;
    for (; k + 1 < dg; k += 2) {
        int s0 = csr[start + k];
        int s1 = csr[start + k + 1];
        unsigned v0 = Yh[(size_t)s0 * 32 + lane];
        unsigned v1 = Yh[(size_t)s1 * 32 + lane];
        float2 f0 = unp2h(v0);
        float2 f1 = unp2h(v1);
        a0 += f0.x; a1 += f0.y;
        b0 += f1.x; b1 += f1.y;
    }
    if (k < dg) {
        int s0 = csr[start + k];
        float2 f0 = unp2h(Yh[(size_t)s0 * 32 + lane]);
        a0 += f0.x; a1 += f0.y;
    }
    a0 += b0;
    a1 += b1;
    float inv = 1.0f / (float)max(dg, 1);
    aggh[(size_t)node * 32 + lane] = pack2h(a0 * inv, a1 * inv);
}

// K4: epilogue: h = relu(agg + bl1 + d); s = h.wA; t = h.wB (8-lane groups)
__global__ __launch_bounds__(256) void epilogue2(const unsigned int* __restrict__ aggh,
                                                 const unsigned int* __restrict__ Dh,
                                                 const float* __restrict__ smalls,
                                                 float* __restrict__ sArr,
                                                 float* __restrict__ tArr)
{
    int t  = threadIdx.x;
    int ng = t >> 3;          // 0..31 node-in-block
    int fg = t & 7;           // feature group
    int node = blockIdx.x * 32 + ng;
    if (node >= N1V) return;

    uint4 av = *(const uint4*)(aggh + (size_t)node * 32 + fg * 4);
    uint4 dv = *(const uint4*)(Dh   + (size_t)node * 32 + fg * 4);

    const float* blp = smalls + fg * 8;
    const float* wAp = smalls + FP + fg * 8;
    const float* wBp = smalls + 2 * FP + fg * 8;

    float af[8], df[8];
    { float2 f; f = unp2h(av.x); af[0]=f.x; af[1]=f.y;
      f = unp2h(av.y); af[2]=f.x; af[3]=f.y;
      f = unp2h(av.z); af[4]=f.x; af[5]=f.y;
      f = unp2h(av.w); af[6]=f.x; af[7]=f.y;
      f = unp2h(dv.x); df[0]=f.x; df[1]=f.y;
      f = unp2h(dv.y); df[2]=f.x; df[3]=f.y;
      f = unp2h(dv.z); df[4]=f.x; df[5]=f.y;
      f = unp2h(dv.w); df[6]=f.x; df[7]=f.y; }

    float s_acc = 0.f, t_acc = 0.f;
#pragma unroll
    for (int j = 0; j < 8; ++j) {
        float h = fmaxf(af[j] + blp[j] + df[j], 0.f);
        s_acc = fmaf(h, wAp[j], s_acc);
        t_acc = fmaf(h, wBp[j], t_acc);
    }
#pragma unroll
    for (int m = 1; m < 8; m <<= 1) {
        s_acc += __shfl_xor(s_acc, m);
        t_acc += __shfl_xor(t_acc, m);
    }
    if (fg == 0) {
        sArr[node] = s_acc;
        if (node < N2V) tArr[node] = t_acc;
    }
}

// K5: edge scatter layer 2 (scalar atomics; only 500k edges)
__global__ __launch_bounds__(256) void scatter2(const float* __restrict__ sArr,
                                                const int* __restrict__ src,
                                                const int* __restrict__ dst,
                                                float* __restrict__ ssum,
                                                float* __restrict__ cnt2)
{
    int e = blockIdx.x * 256 + threadIdx.x;
    if (e >= E1V) return;
    int sI = src[e];
    int dI = dst[e];
    atomicAdd(&ssum[dI], sArr[sI]);
    atomicAdd(&cnt2[dI], 1.0f);
}

// K6: out[i] = relu(ssum[i]/max(cnt2,1) + t[i] + c)
__global__ __launch_bounds__(256) void final_out(const float* __restrict__ ssum,
                                                 const float* __restrict__ cnt2,
                                                 const float* __restrict__ tArr,
                                                 const float* __restrict__ smalls,
                                                 float* __restrict__ out)
{
    int i = blockIdx.x * 256 + threadIdx.x;
    if (i >= N2V) return;
    float c = smalls[3 * FP];
    float inv = 1.0f / fmaxf(cnt2[i], 1.0f);
    float o = fmaf(ssum[i], inv, tArr[i] + c);
    out[i] = fmaxf(o, 0.f);
}

extern "C" void kernel_launch(void* const* d_in, const int* in_sizes, int n_in,
                              void* d_out, int out_size, void* d_ws, size_t ws_size,
                              hipStream_t stream)
{
    if (ws_size < WS_NEEDED) return;

    const float* x    = (const float*)d_in[0];
    const int*   src0 = (const int*)d_in[2];
    const int*   dst0 = (const int*)d_in[3];
    const int*   src1 = (const int*)d_in[4];
    const int*   dst1 = (const int*)d_in[5];
    const float* Wl1  = (const float*)d_in[8];
    const float* bl1  = (const float*)d_in[9];
    const float* Wr1  = (const float*)d_in[10];
    const float* Wl2  = (const float*)d_in[11];
    const float* bl2  = (const float*)d_in[12];
    const float* Wr2  = (const float*)d_in[13];
    const float* Wo   = (const float*)d_in[14];
    const float* bo   = (const float*)d_in[15];
    float* out = (float*)d_out;

    char* ws = (char*)d_ws;
    int*   deg    = (int*)(ws + OFF_DEG);
    float* ssum   = (float*)(ws + OFF_SSUM);
    float* cnt2   = (float*)(ws + OFF_CNT2);
    int*   rowptr = (int*)(ws + OFF_ROWPTR);
    int*   cursor = (int*)(ws + OFF_CURSOR);
    int*   bsum   = (int*)(ws + OFF_BSUM);
    float* smalls = (float*)(ws + OFF_SMALL);
    _Float16* Wlt = (_Float16*)(ws + OFF_WLT);
    _Float16* Wrt = (_Float16*)(ws + OFF_WRT);
    float* sArr   = (float*)(ws + OFF_S);
    float* tArr   = (float*)(ws + OFF_T);
    int*   csr    = (int*)(ws + OFF_CSR);
    unsigned int* aggh = (unsigned int*)(ws + OFF_AGG);
    unsigned int* Dh   = (unsigned int*)(ws + OFF_D);
    unsigned int* Yh   = (unsigned int*)(ws + OFF_Y);

    hipMemsetAsync(d_ws, 0, ZERO_BYTES, stream);

    pad_w<<<32, 256, 0, stream>>>(Wl1, Wr1, bl1, Wl2, bl2, Wr2, Wo, bo, Wlt, Wrt, smalls);

    fused_gemm<<<(N0V + 127) / 128, 256, 0, stream>>>(x, Wlt, Wrt, Yh, Dh);

    // CSR build for layer-1 edges
    hist1<<<(E0V + 255) / 256, 256, 0, stream>>>(dst0, deg);
    scan_a<<<NB_SCAN, 256, 0, stream>>>(deg, rowptr, bsum);
    scan_b<<<1, 256, 0, stream>>>(bsum);
    scan_c<<<NB_SCAN, 256, 0, stream>>>(deg, rowptr, cursor, bsum);
    fill1<<<(E0V + 255) / 256, 256, 0, stream>>>(src0, dst0, cursor, csr);

    gather1<<<(N1V + 7) / 8, 256, 0, stream>>>(Yh, rowptr, deg, csr, aggh);

    epilogue2<<<(N1V + 31) / 32, 256, 0, stream>>>(aggh, Dh, smalls, sArr, tArr);

    scatter2<<<(E1V + 255) / 256, 256, 0, stream>>>(sArr, src1, dst1, ssum, cnt2);

    final_out<<<(N2V + 255) / 256, 256, 0, stream>>>(ssum, cnt2, tArr, smalls, out);
}